// Round 12
// baseline (377.356 us; speedup 1.0000x reference)
//
#include <hip/hip_runtime.h>
#include <hip/hip_bf16.h>

// GCN 2-layer on MI355X — global-atomic-free CSR build + register-acc aggregation.
// R5: global atomicAdd walled ~24 ops/ns device-wide -> no global atomics.
// R6: bucketed LDS-atomic aggregation FAILED (no TLP + in-order LDS pipe).
// R7/R8: hist->scan->part->sort2 CSR + wave-per-node register-acc agg.
// R9/R10: MFMA gemm spill-bound at 98us (frag cache > VGPR budget).
// R11: LDS-free MFMA gemm (wT in ws, frags as L2-hot global loads) -> gemm off
//      top-5. k_agg1 now the wall: 89us, 292MB fetch @ 3.36 TB/s, VALUBusy 51%.
//      Limiter = gather queue entries (1 ushort-load/edge = 128B/entry) + per-
//      edge ds_bpermute broadcast.
// R12: wide-gather agg1: lane = (edge-slot g, feature-quad f); one dwordx2
//      wave-load = 4 edge rows (512B/entry, 4x fewer entries/byte); no shfl
//      broadcast (uniform srcSorted loads; 2 shfl_xor combine at end). Tail
//      edges -> zero row at hb[N] (written by gemm kernels).

typedef short s8_t __attribute__((ext_vector_type(8)));
typedef float f4_t __attribute__((ext_vector_type(4)));
typedef unsigned short u4_t __attribute__((ext_vector_type(4)));

__device__ __forceinline__ float bf2f(unsigned short u) {
    union { unsigned int u; float f; } c; c.u = ((unsigned int)u) << 16; return c.f;
}
__device__ __forceinline__ unsigned short f2bf(float f) {
    union { float f; unsigned int u; } c; c.f = f;
    unsigned int u = c.u;
    unsigned int r = (u + 0x7fffu + ((u >> 16) & 1u)) >> 16;  // round-nearest-even
    return (unsigned short)r;
}
__device__ __forceinline__ float loadF(const void* p, int i, int isbf) {
    return isbf ? bf2f(((const unsigned short*)p)[i]) : ((const float*)p)[i];
}
__device__ __forceinline__ int edgeIdx(const void* e, long long i, int is64) {
    return is64 ? (int)((const long long*)e)[i] : ((const int*)e)[i];
}

// flags[0] = edge indices are int64; flags[1] = float tensors are bf16
__global__ void k_detect(const void* e, const void* x, int* flags) {
    int lane = threadIdx.x;  // blockDim = 64
    unsigned int ew = ((const unsigned int*)e)[2 * lane + 1];
    unsigned long long nz = __ballot(ew != 0);
    unsigned int xw = ((const unsigned int*)x)[lane];
    unsigned int low = xw & 0xffffu;
    unsigned int e8 = (low >> 7) & 0xffu;
    bool plaus = (low == 0u) || (e8 >= 110u && e8 <= 135u);
    unsigned long long pl = __ballot(plaus);
    if (lane == 0) {
        flags[0] = (nz == 0ull) ? 1 : 0;
        flags[1] = (__popcll(pl) > 32) ? 1 : 0;
    }
}

// W1^T into workspace (bf16 only): wT[n][k] = W1[k][n]. 64x128 ushorts.
__global__ void k_prep(const void* W1, unsigned short* __restrict__ wT,
                       const int* flags) {
    if (!flags[1]) return;
    int tid = threadIdx.x;
    const unsigned short* w = (const unsigned short*)W1;
    for (int idx = tid; idx < 128 * 64; idx += 256) {
        int k = idx >> 6, n = idx & 63;
        wT[n * 128 + k] = w[idx];
    }
}

// Per-block LDS histogram over B coarse buckets (dst>>7); hist[bucket][block].
__launch_bounds__(256)
__global__ void k_hist(const void* e, int* __restrict__ histT, const int* flags,
                       int E, int B, int HB) {
    __shared__ int hist[1024];
    int tid = threadIdx.x;
    int is64 = flags[0];
    for (int f = tid; f < B; f += 256) hist[f] = 0;
    __syncthreads();
    int base = blockIdx.x * 4096;
    #pragma unroll
    for (int k = 0; k < 16; ++k) {
        int i = base + k * 256 + tid;
        if (i < E) {
            int d = edgeIdx(e, (long long)E + i, is64);
            atomicAdd(&hist[d >> 7], 1);   // LDS atomic
        }
    }
    __syncthreads();
    for (int f = tid; f < B; f += 256)
        histT[(long long)f * HB + blockIdx.x] = hist[f];
}

// Exclusive scan over M = B*HB ints, level A.
__global__ void k_scanA(int* __restrict__ data, int* __restrict__ partial, int M) {
    __shared__ int s[256];
    int tid = threadIdx.x;
    int i = blockIdx.x * 256 + tid;
    int v = (i < M) ? data[i] : 0;
    s[tid] = v; __syncthreads();
    for (int off = 1; off < 256; off <<= 1) {
        int t = (tid >= off) ? s[tid - off] : 0;
        __syncthreads(); s[tid] += t; __syncthreads();
    }
    if (i < M) data[i] = s[tid] - v;
    if (tid == 255) partial[blockIdx.x] = s[255];
}

// Level B: in-place exclusive scan of nP partials (nP <= 8192).
__global__ void k_scanB(int* __restrict__ partial, int nP) {
    __shared__ int s[1024];
    int tid = threadIdx.x;
    int C = (nP + 1023) >> 10;
    int base = tid * C;
    int v[8]; int tot = 0;
    for (int j = 0; j < C; ++j) { v[j] = (base + j < nP) ? partial[base + j] : 0; tot += v[j]; }
    s[tid] = tot; __syncthreads();
    for (int off = 1; off < 1024; off <<= 1) {
        int t = (tid >= off) ? s[tid - off] : 0;
        __syncthreads(); s[tid] += t; __syncthreads();
    }
    int run = s[tid] - tot;
    for (int j = 0; j < C; ++j) { if (base + j < nP) { int tmp = v[j]; partial[base + j] = run; run += tmp; } }
}

// Level C: add block bases; extract bucketStart.
__global__ void k_scanC(int* __restrict__ data, const int* __restrict__ partial,
                        int* __restrict__ bucketStart, int M, int HB, int B, int E) {
    int f = blockIdx.x * 256 + threadIdx.x;
    if (f < M) {
        int val = data[f] + partial[f >> 8];
        data[f] = val;
        int q = f / HB;
        if (f - q * HB == 0) bucketStart[q] = val;
    }
    if (f == 0) bucketStart[B] = E;
}

// Partition: pos = scanned[bucket][block] + LDS-atomic rank.
// part[pos] = src | (dstLocal << 20)   (requires N < 2^20).
__launch_bounds__(256)
__global__ void k_part(const void* e, const int* __restrict__ histT,
                       int* __restrict__ part, const int* flags,
                       int E, int B, int HB) {
    __shared__ int lcur[1024];
    int tid = threadIdx.x;
    int is64 = flags[0];
    for (int f = tid; f < B; f += 256)
        lcur[f] = histT[(long long)f * HB + blockIdx.x];
    __syncthreads();
    int base = blockIdx.x * 4096;
    #pragma unroll
    for (int k = 0; k < 16; ++k) {
        int i = base + k * 256 + tid;
        if (i < E) {
            int s = edgeIdx(e, i, is64);
            int d = edgeIdx(e, (long long)E + i, is64);
            int pos = atomicAdd(&lcur[d >> 7], 1);   // LDS atomic
            part[pos] = s | ((d & 127) << 20);
        }
    }
}

// Block-per-bucket second sort: LDS 128-counter hist + LDS-rank scatter ->
// fully dst-sorted srcSorted[]; write start[node] and dinv[node].
__launch_bounds__(256)
__global__ void k_sort2(const int* __restrict__ part, const int* __restrict__ bucketStart,
                        int* __restrict__ srcSorted, int* __restrict__ start,
                        float* __restrict__ dinv, int N, int B) {
    __shared__ int cnt[128];
    __shared__ int basel[128];
    __shared__ int cur[128];
    int tid = threadIdx.x, b = blockIdx.x;
    if (tid < 128) cnt[tid] = 0;
    __syncthreads();
    int lo = bucketStart[b], hi = bucketStart[b + 1];
    for (int idx = lo + tid; idx < hi; idx += 256)
        atomicAdd(&cnt[(part[idx] >> 20) & 127], 1);
    __syncthreads();
    if (tid == 0) {
        int run = lo;
        for (int j = 0; j < 128; ++j) { basel[j] = run; run += cnt[j]; }
    }
    __syncthreads();
    if (tid < 128) {
        cur[tid] = basel[tid];
        int node = b * 128 + tid;
        if (node < N) {
            start[node] = basel[tid];
            dinv[node] = rsqrtf((float)(cnt[tid] + 1));  // +1 self-loop
        }
    }
    if (b == 0 && tid == 0) start[N] = bucketStart[B];  // = E
    __syncthreads();
    for (int idx = lo + tid; idx < hi; idx += 256) {
        int pw = part[idx];
        int pos = atomicAdd(&cur[(pw >> 20) & 127], 1);  // LDS atomic w/ return
        srcSorted[pos] = pw & 0xFFFFF;
    }
}

// bf16 MFMA GEMM, LDS-FREE: hb[row][n] = bf16((x@W1)[row][n] * dinv[row]).
// Also zeroes hb row N (the agg1 tail sink). Early-exit if not bf16.
__launch_bounds__(256)
__global__ void k_gemm_bf(const void* x, const unsigned short* __restrict__ wT,
                          const float* __restrict__ dinv,
                          unsigned short* __restrict__ hb, const int* flags, int N) {
    if (!flags[1]) return;
    int tid = threadIdx.x;
    if (blockIdx.x == 0 && tid < 64) hb[(long long)N * 64 + tid] = 0;  // zero row
    int lane = tid & 63, wv = tid >> 6;
    int q = lane >> 4, r = lane & 15;
    const unsigned short* xb = (const unsigned short*)x;
    int gw = blockIdx.x * 4 + wv;
    int nW = gridDim.x * 4;
    int RB = (N + 15) >> 4;
    for (int rb = gw; rb < RB; rb += nW) {
        int row0 = rb * 16;
        int arow = row0 + r;
        s8_t a[4];
        #pragma unroll
        for (int kk = 0; kk < 4; ++kk)
            a[kk] = (arow < N)
                ? *(const s8_t*)&xb[(long long)arow * 128 + kk * 32 + q * 8]
                : (s8_t)(short)0;
        f4_t acc[4];
        #pragma unroll
        for (int nt = 0; nt < 4; ++nt) acc[nt] = (f4_t){0.f, 0.f, 0.f, 0.f};
        #pragma unroll
        for (int nt = 0; nt < 4; ++nt) {
            #pragma unroll
            for (int kk = 0; kk < 4; ++kk) {
                s8_t b = *(const s8_t*)&wT[(nt * 16 + r) * 128 + kk * 32 + q * 8];
                acc[nt] = __builtin_amdgcn_mfma_f32_16x16x32_bf16(a[kk], b, acc[nt], 0, 0, 0);
            }
        }
        #pragma unroll
        for (int reg = 0; reg < 4; ++reg) {
            int row = row0 + q * 4 + reg;
            if (row < N) {
                float dv = dinv[row];
                #pragma unroll
                for (int nt = 0; nt < 4; ++nt)
                    hb[(long long)row * 64 + nt * 16 + r] = f2bf(acc[nt][reg] * dv);
            }
        }
    }
}

// f32 fallback GEMM (LDS-VALU loop). Early-exit if bf16. Also zeroes hb row N.
__launch_bounds__(256)
__global__ void k_gemm_f32(const void* x, const void* W1, const float* __restrict__ dinv,
                           unsigned short* __restrict__ hb, const int* flags, int N) {
    if (flags[1]) return;
    __shared__ float Wl[128 * 64];
    __shared__ float xr[4][128];
    int tid = threadIdx.x;
    if (blockIdx.x == 0 && tid < 64) hb[(long long)N * 64 + tid] = 0;  // zero row
    for (int idx = tid; idx < 128 * 64; idx += 256) Wl[idx] = ((const float*)W1)[idx];
    int w = tid >> 6, lane = tid & 63;
    for (int rb = blockIdx.x * 4; rb < N; rb += gridDim.x * 4) {
        int row = rb + w;
        bool active = row < N;
        __syncthreads();
        if (active) {
            xr[w][lane]      = ((const float*)x)[(long long)row * 128 + lane];
            xr[w][lane + 64] = ((const float*)x)[(long long)row * 128 + 64 + lane];
        }
        __syncthreads();
        if (active) {
            float acc = 0.f;
            #pragma unroll
            for (int k = 0; k < 128; ++k)
                acc += xr[w][k] * Wl[k * 64 + lane];
            hb[(long long)row * 64 + lane] = f2bf(acc * dinv[row]);
        }
    }
}

// Layer-1 aggregation + epilogue, wave-per-node, WIDE gathers.
// lane = 16*g + f: g = edge slot (0..3), f = feature quad (features 4f..4f+3).
// One dwordx2 wave-load = 4 edge rows (512 B). Invalid slots -> zero row N.
// Cross-group combine: shfl_xor 32,16. Epilogue per feature-quad, f-reduce.
__launch_bounds__(256)
__global__ void k_agg1(const unsigned short* __restrict__ hb,
                       const float* __restrict__ dinv,
                       const int* __restrict__ start,
                       const int* __restrict__ srcSorted,
                       const void* b1, const void* W2, float* __restrict__ sbuf2,
                       const int* flags, int N) {
    int lane = threadIdx.x & 63;
    int node = (blockIdx.x * blockDim.x + threadIdx.x) >> 6;
    if (node >= N) return;
    int isbf = flags[1];
    int g = lane >> 4, f = lane & 15;
    float di = dinv[node];
    int base = start[node], cnt = start[node + 1] - base;
    float a0 = 0.f, a1 = 0.f, a2 = 0.f, a3 = 0.f;
    // self row: group 0 only (counted once after cross-group combine)
    u4_t sv = *(const u4_t*)&hb[(long long)node * 64 + 4 * f];
    if (g == 0) {
        a0 += bf2f(sv.x); a1 += bf2f(sv.y); a2 += bf2f(sv.z); a3 += bf2f(sv.w);
    }
    for (int c = 0; c < cnt; c += 16) {
        int i0, i1, i2, i3;
        {
            int t = c + g;          int tc = t < cnt ? t : cnt - 1;
            int si = srcSorted[base + tc]; i0 = t < cnt ? si : N;
        }
        {
            int t = c + 4 + g;      int tc = t < cnt ? t : cnt - 1;
            int si = srcSorted[base + tc]; i1 = t < cnt ? si : N;
        }
        {
            int t = c + 8 + g;      int tc = t < cnt ? t : cnt - 1;
            int si = srcSorted[base + tc]; i2 = t < cnt ? si : N;
        }
        {
            int t = c + 12 + g;     int tc = t < cnt ? t : cnt - 1;
            int si = srcSorted[base + tc]; i3 = t < cnt ? si : N;
        }
        u4_t r0 = *(const u4_t*)&hb[(long long)i0 * 64 + 4 * f];
        u4_t r1 = *(const u4_t*)&hb[(long long)i1 * 64 + 4 * f];
        u4_t r2 = *(const u4_t*)&hb[(long long)i2 * 64 + 4 * f];
        u4_t r3 = *(const u4_t*)&hb[(long long)i3 * 64 + 4 * f];
        a0 += bf2f(r0.x); a1 += bf2f(r0.y); a2 += bf2f(r0.z); a3 += bf2f(r0.w);
        a0 += bf2f(r1.x); a1 += bf2f(r1.y); a2 += bf2f(r1.z); a3 += bf2f(r1.w);
        a0 += bf2f(r2.x); a1 += bf2f(r2.y); a2 += bf2f(r2.z); a3 += bf2f(r2.w);
        a0 += bf2f(r3.x); a1 += bf2f(r3.y); a2 += bf2f(r3.z); a3 += bf2f(r3.w);
    }
    // combine the 4 edge-slot groups (bits 4,5 of lane)
    a0 += __shfl_xor(a0, 32); a0 += __shfl_xor(a0, 16);
    a1 += __shfl_xor(a1, 32); a1 += __shfl_xor(a1, 16);
    a2 += __shfl_xor(a2, 32); a2 += __shfl_xor(a2, 16);
    a3 += __shfl_xor(a3, 32); a3 += __shfl_xor(a3, 16);
    // epilogue: v = acc*di + b1; relu; p = v . W2  (4 features per lane)
    float p;
    {
        float v0 = fmaxf(a0 * di + loadF(b1, 4 * f + 0, isbf), 0.f);
        float v1 = fmaxf(a1 * di + loadF(b1, 4 * f + 1, isbf), 0.f);
        float v2 = fmaxf(a2 * di + loadF(b1, 4 * f + 2, isbf), 0.f);
        float v3 = fmaxf(a3 * di + loadF(b1, 4 * f + 3, isbf), 0.f);
        p = v0 * loadF(W2, 4 * f + 0, isbf) + v1 * loadF(W2, 4 * f + 1, isbf)
          + v2 * loadF(W2, 4 * f + 2, isbf) + v3 * loadF(W2, 4 * f + 3, isbf);
    }
    p += __shfl_xor(p, 8); p += __shfl_xor(p, 4);
    p += __shfl_xor(p, 2); p += __shfl_xor(p, 1);
    if (lane == 0) sbuf2[node] = p * di;
}

// Layer-2: out[i] = (sum_src sbuf2[src] + sbuf2[i]) * dinv[i] + b2.
__launch_bounds__(256)
__global__ void k_agg2(const float* __restrict__ sbuf2, const float* __restrict__ dinv,
                       const int* __restrict__ start,
                       const int* __restrict__ srcSorted,
                       const void* b2, void* out, const int* flags, int N) {
    int lane = threadIdx.x & 63;
    int node = (blockIdx.x * blockDim.x + threadIdx.x) >> 6;
    if (node >= N) return;
    int isbf = flags[1];
    float di = dinv[node];
    int base = start[node], cnt = start[node + 1] - base;
    float part = 0.f;
    for (int t = lane; t < cnt; t += 64) part += sbuf2[srcSorted[base + t]];
    #pragma unroll
    for (int o = 32; o >= 1; o >>= 1) part += __shfl_xor(part, o);
    if (lane == 0) {
        float o_ = (part + sbuf2[node]) * di + loadF(b2, 0, isbf);
        if (isbf) ((unsigned short*)out)[node] = f2bf(o_);
        else      ((float*)out)[node] = o_;
    }
}

extern "C" void kernel_launch(void* const* d_in, const int* in_sizes, int n_in,
                              void* d_out, int out_size, void* d_ws, size_t ws_size,
                              hipStream_t stream) {
    const void* x  = d_in[0];
    const void* e  = d_in[1];
    const void* W1 = d_in[2];
    const void* b1 = d_in[3];
    const void* W2 = d_in[4];
    const void* b2 = d_in[5];
    int N = in_sizes[0] / 128;     // 100000
    int E = in_sizes[1] / 2;       // 3200000
    int B  = (N + 127) / 128;      // 782 buckets (<=1024)
    int HB = (E + 4095) / 4096;    // 782 hist blocks
    int M  = B * HB;               // 611,524
    int nP = (M + 255) / 256;      // 2389 (<=8192)
    int NB = B * 128;              // 100,096 padded nodes
    int EP = ((E + 255) / 256) * 256;
    int RB = (N + 15) / 16;        // 6250 row-blocks
    int GG = (RB + 3) / 4;         // 1563 blocks: one row-block per wave

    // Workspace (~29.5 MB; 40.4 MB proven safe, 52.8 MB crashes):
    int*   wsI         = (int*)d_ws;
    int*   flags       = wsI;                              // 256
    unsigned short* wT = (unsigned short*)(wsI + 256);     // 8192 ushorts (16KB)
    int*   histT       = wsI + 256 + 4096;                 // M rounded
    int*   partial     = histT + ((M + 255) / 256) * 256;  // nP rounded
    int*   bucketStart = partial + ((nP + 255) / 256) * 256;  // B+1 -> 1040
    float* dinv        = (float*)(bucketStart + 1040);     // NB
    float* sbuf2       = dinv + NB;                        // NB
    int*   start       = (int*)(sbuf2 + NB);               // NB + 256
    int*   srcSorted   = start + NB + 256;                 // EP
    int*   part        = srcSorted + EP;                   // EP (12.8 MB)
    unsigned short* hb = (unsigned short*)part;            // (N+1)*64 bf16, ALIASES part

    hipLaunchKernelGGL(k_detect, dim3(1), dim3(64), 0, stream, e, x, flags);
    hipLaunchKernelGGL(k_prep, dim3(1), dim3(256), 0, stream, W1, wT, flags);
    hipLaunchKernelGGL(k_hist, dim3(HB), dim3(256), 0, stream, e, histT, flags, E, B, HB);
    hipLaunchKernelGGL(k_scanA, dim3(nP), dim3(256), 0, stream, histT, partial, M);
    hipLaunchKernelGGL(k_scanB, dim3(1), dim3(1024), 0, stream, partial, nP);
    hipLaunchKernelGGL(k_scanC, dim3(nP), dim3(256), 0, stream,
                       histT, partial, bucketStart, M, HB, B, E);
    hipLaunchKernelGGL(k_part, dim3(HB), dim3(256), 0, stream, e, histT, part, flags, E, B, HB);
    hipLaunchKernelGGL(k_sort2, dim3(B), dim3(256), 0, stream,
                       part, bucketStart, srcSorted, start, dinv, N, B);
    hipLaunchKernelGGL(k_gemm_bf, dim3(GG), dim3(256), 0, stream,
                       x, wT, dinv, hb, flags, N);
    hipLaunchKernelGGL(k_gemm_f32, dim3(2048), dim3(256), 0, stream,
                       x, W1, dinv, hb, flags, N);
    hipLaunchKernelGGL(k_agg1, dim3((N + 3) / 4), dim3(256), 0, stream,
                       hb, dinv, start, srcSorted, b1, W2, sbuf2, flags, N);
    hipLaunchKernelGGL(k_agg2, dim3((N + 3) / 4), dim3(256), 0, stream,
                       sbuf2, dinv, start, srcSorted, b2, d_out, flags, N);
}

// Round 13
// 362.374 us; speedup vs baseline: 1.0413x; 1.0413x over previous
//
#include <hip/hip_runtime.h>
#include <hip/hip_bf16.h>

// GCN 2-layer on MI355X — global-atomic-free CSR build + register-acc aggregation.
// R5: global atomicAdd walled ~24 ops/ns device-wide -> no global atomics.
// R6: bucketed LDS-atomic aggregation FAILED (no TLP + in-order LDS pipe).
// R7/R8: hist->scan->part->sort2 CSR + wave-per-node register-acc agg.
// R9/R10: MFMA gemm spill-bound at 98us (frag cache > VGPR budget).
// R11: LDS-free MFMA gemm -> gemm off top-5; agg1 89us @ 3.36 TB/s.
// R12: wide-gather agg1 REGRESSED (99.8us): broadcast index loads entered the
//      gather dependency chain. Reverted to R11 agg1 (shfl-broadcast batches).
// R13: coarser buckets (512 nodes, B=196): k_part write runs 5->21 ints
//      (sub-line 21B -> 84B, less write amplification); sort2 with 512 LDS
//      counters + parallel scan; pack src | dstLocal<<17 (N < 2^17).

typedef short s8_t __attribute__((ext_vector_type(8)));
typedef float f4_t __attribute__((ext_vector_type(4)));

__device__ __forceinline__ float bf2f(unsigned short u) {
    union { unsigned int u; float f; } c; c.u = ((unsigned int)u) << 16; return c.f;
}
__device__ __forceinline__ unsigned short f2bf(float f) {
    union { float f; unsigned int u; } c; c.f = f;
    unsigned int u = c.u;
    unsigned int r = (u + 0x7fffu + ((u >> 16) & 1u)) >> 16;  // round-nearest-even
    return (unsigned short)r;
}
__device__ __forceinline__ float loadF(const void* p, int i, int isbf) {
    return isbf ? bf2f(((const unsigned short*)p)[i]) : ((const float*)p)[i];
}
__device__ __forceinline__ int edgeIdx(const void* e, long long i, int is64) {
    return is64 ? (int)((const long long*)e)[i] : ((const int*)e)[i];
}

// flags[0] = edge indices are int64; flags[1] = float tensors are bf16
__global__ void k_detect(const void* e, const void* x, int* flags) {
    int lane = threadIdx.x;  // blockDim = 64
    unsigned int ew = ((const unsigned int*)e)[2 * lane + 1];
    unsigned long long nz = __ballot(ew != 0);
    unsigned int xw = ((const unsigned int*)x)[lane];
    unsigned int low = xw & 0xffffu;
    unsigned int e8 = (low >> 7) & 0xffu;
    bool plaus = (low == 0u) || (e8 >= 110u && e8 <= 135u);
    unsigned long long pl = __ballot(plaus);
    if (lane == 0) {
        flags[0] = (nz == 0ull) ? 1 : 0;
        flags[1] = (__popcll(pl) > 32) ? 1 : 0;
    }
}

// W1^T into workspace (bf16 only): wT[n][k] = W1[k][n]. 64x128 ushorts.
__global__ void k_prep(const void* W1, unsigned short* __restrict__ wT,
                       const int* flags) {
    if (!flags[1]) return;
    int tid = threadIdx.x;
    const unsigned short* w = (const unsigned short*)W1;
    for (int idx = tid; idx < 128 * 64; idx += 256) {
        int k = idx >> 6, n = idx & 63;
        wT[n * 128 + k] = w[idx];
    }
}

// Per-block LDS histogram over B coarse buckets (dst>>9); hist[bucket][block].
__launch_bounds__(256)
__global__ void k_hist(const void* e, int* __restrict__ histT, const int* flags,
                       int E, int B, int HB) {
    __shared__ int hist[1024];
    int tid = threadIdx.x;
    int is64 = flags[0];
    for (int f = tid; f < B; f += 256) hist[f] = 0;
    __syncthreads();
    int base = blockIdx.x * 4096;
    #pragma unroll
    for (int k = 0; k < 16; ++k) {
        int i = base + k * 256 + tid;
        if (i < E) {
            int d = edgeIdx(e, (long long)E + i, is64);
            atomicAdd(&hist[d >> 9], 1);   // LDS atomic
        }
    }
    __syncthreads();
    for (int f = tid; f < B; f += 256)
        histT[(long long)f * HB + blockIdx.x] = hist[f];
}

// Exclusive scan over M = B*HB ints, level A.
__global__ void k_scanA(int* __restrict__ data, int* __restrict__ partial, int M) {
    __shared__ int s[256];
    int tid = threadIdx.x;
    int i = blockIdx.x * 256 + tid;
    int v = (i < M) ? data[i] : 0;
    s[tid] = v; __syncthreads();
    for (int off = 1; off < 256; off <<= 1) {
        int t = (tid >= off) ? s[tid - off] : 0;
        __syncthreads(); s[tid] += t; __syncthreads();
    }
    if (i < M) data[i] = s[tid] - v;
    if (tid == 255) partial[blockIdx.x] = s[255];
}

// Level B: in-place exclusive scan of nP partials (nP <= 8192).
__global__ void k_scanB(int* __restrict__ partial, int nP) {
    __shared__ int s[1024];
    int tid = threadIdx.x;
    int C = (nP + 1023) >> 10;
    int base = tid * C;
    int v[8]; int tot = 0;
    for (int j = 0; j < C; ++j) { v[j] = (base + j < nP) ? partial[base + j] : 0; tot += v[j]; }
    s[tid] = tot; __syncthreads();
    for (int off = 1; off < 1024; off <<= 1) {
        int t = (tid >= off) ? s[tid - off] : 0;
        __syncthreads(); s[tid] += t; __syncthreads();
    }
    int run = s[tid] - tot;
    for (int j = 0; j < C; ++j) { if (base + j < nP) { int tmp = v[j]; partial[base + j] = run; run += tmp; } }
}

// Level C: add block bases; extract bucketStart.
__global__ void k_scanC(int* __restrict__ data, const int* __restrict__ partial,
                        int* __restrict__ bucketStart, int M, int HB, int B, int E) {
    int f = blockIdx.x * 256 + threadIdx.x;
    if (f < M) {
        int val = data[f] + partial[f >> 8];
        data[f] = val;
        int q = f / HB;
        if (f - q * HB == 0) bucketStart[q] = val;
    }
    if (f == 0) bucketStart[B] = E;
}

// Partition: pos = scanned[bucket][block] + LDS-atomic rank.
// part[pos] = src | (dstLocal << 17)   (requires N <= 2^17).
__launch_bounds__(256)
__global__ void k_part(const void* e, const int* __restrict__ histT,
                       int* __restrict__ part, const int* flags,
                       int E, int B, int HB) {
    __shared__ int lcur[1024];
    int tid = threadIdx.x;
    int is64 = flags[0];
    for (int f = tid; f < B; f += 256)
        lcur[f] = histT[(long long)f * HB + blockIdx.x];
    __syncthreads();
    int base = blockIdx.x * 4096;
    #pragma unroll
    for (int k = 0; k < 16; ++k) {
        int i = base + k * 256 + tid;
        if (i < E) {
            int s = edgeIdx(e, i, is64);
            int d = edgeIdx(e, (long long)E + i, is64);
            int pos = atomicAdd(&lcur[d >> 9], 1);   // LDS atomic
            part[pos] = s | ((d & 511) << 17);
        }
    }
}

// Block-per-bucket second sort (512 nodes/bucket): LDS 512-counter hist +
// parallel exclusive scan + LDS-rank scatter -> dst-sorted srcSorted[];
// write start[node] and dinv[node].
__launch_bounds__(512)
__global__ void k_sort2(const int* __restrict__ part, const int* __restrict__ bucketStart,
                        int* __restrict__ srcSorted, int* __restrict__ start,
                        float* __restrict__ dinv, int N, int B) {
    __shared__ int cnt[512];
    __shared__ int s[512];
    __shared__ int cur[512];
    int tid = threadIdx.x, b = blockIdx.x;
    cnt[tid] = 0;
    __syncthreads();
    int lo = bucketStart[b], hi = bucketStart[b + 1];
    for (int idx = lo + tid; idx < hi; idx += 512)
        atomicAdd(&cnt[(part[idx] >> 17) & 511], 1);
    __syncthreads();
    int v = cnt[tid];
    s[tid] = v; __syncthreads();
    for (int off = 1; off < 512; off <<= 1) {
        int t = (tid >= off) ? s[tid - off] : 0;
        __syncthreads(); s[tid] += t; __syncthreads();
    }
    int base_ = lo + s[tid] - v;   // exclusive-scan position
    cur[tid] = base_;
    int node = b * 512 + tid;
    if (node < N) {
        start[node] = base_;
        dinv[node] = rsqrtf((float)(v + 1));  // +1 self-loop
    }
    if (b == 0 && tid == 0) start[N] = bucketStart[B];  // = E
    __syncthreads();
    for (int idx = lo + tid; idx < hi; idx += 512) {
        int pw = part[idx];
        int pos = atomicAdd(&cur[(pw >> 17) & 511], 1);  // LDS atomic w/ return
        srcSorted[pos] = pw & 0x1FFFF;
    }
}

// bf16 MFMA GEMM, LDS-FREE: hb[row][n] = bf16((x@W1)[row][n] * dinv[row]).
// A[m=lane&15][k=q*8+j]; B[n=lane&15][k=q*8+j] from wT (L2-hot 16KB);
// C/D col=lane&15, row=q*4+reg. One 16-row block per wave. Early-exit if f32.
// NOTE: hb aliases part[] — runs after k_sort2 consumed part.
__launch_bounds__(256)
__global__ void k_gemm_bf(const void* x, const unsigned short* __restrict__ wT,
                          const float* __restrict__ dinv,
                          unsigned short* __restrict__ hb, const int* flags, int N) {
    if (!flags[1]) return;
    int tid = threadIdx.x;
    int lane = tid & 63, wv = tid >> 6;
    int q = lane >> 4, r = lane & 15;
    const unsigned short* xb = (const unsigned short*)x;
    int gw = blockIdx.x * 4 + wv;
    int nW = gridDim.x * 4;
    int RB = (N + 15) >> 4;
    for (int rb = gw; rb < RB; rb += nW) {
        int row0 = rb * 16;
        int arow = row0 + r;
        s8_t a[4];
        #pragma unroll
        for (int kk = 0; kk < 4; ++kk)
            a[kk] = (arow < N)
                ? *(const s8_t*)&xb[(long long)arow * 128 + kk * 32 + q * 8]
                : (s8_t)(short)0;
        f4_t acc[4];
        #pragma unroll
        for (int nt = 0; nt < 4; ++nt) acc[nt] = (f4_t){0.f, 0.f, 0.f, 0.f};
        #pragma unroll
        for (int nt = 0; nt < 4; ++nt) {
            #pragma unroll
            for (int kk = 0; kk < 4; ++kk) {
                s8_t b = *(const s8_t*)&wT[(nt * 16 + r) * 128 + kk * 32 + q * 8];
                acc[nt] = __builtin_amdgcn_mfma_f32_16x16x32_bf16(a[kk], b, acc[nt], 0, 0, 0);
            }
        }
        #pragma unroll
        for (int reg = 0; reg < 4; ++reg) {
            int row = row0 + q * 4 + reg;
            if (row < N) {
                float dv = dinv[row];
                #pragma unroll
                for (int nt = 0; nt < 4; ++nt)
                    hb[(long long)row * 64 + nt * 16 + r] = f2bf(acc[nt][reg] * dv);
            }
        }
    }
}

// f32 fallback GEMM (LDS-VALU loop). Early-exit if bf16.
__launch_bounds__(256)
__global__ void k_gemm_f32(const void* x, const void* W1, const float* __restrict__ dinv,
                           unsigned short* __restrict__ hb, const int* flags, int N) {
    if (flags[1]) return;
    __shared__ float Wl[128 * 64];
    __shared__ float xr[4][128];
    int tid = threadIdx.x;
    for (int idx = tid; idx < 128 * 64; idx += 256) Wl[idx] = ((const float*)W1)[idx];
    int w = tid >> 6, lane = tid & 63;
    for (int rb = blockIdx.x * 4; rb < N; rb += gridDim.x * 4) {
        int row = rb + w;
        bool active = row < N;
        __syncthreads();
        if (active) {
            xr[w][lane]      = ((const float*)x)[(long long)row * 128 + lane];
            xr[w][lane + 64] = ((const float*)x)[(long long)row * 128 + 64 + lane];
        }
        __syncthreads();
        if (active) {
            float acc = 0.f;
            #pragma unroll
            for (int k = 0; k < 128; ++k)
                acc += xr[w][k] * Wl[k * 64 + lane];
            hb[(long long)row * 64 + lane] = f2bf(acc * dinv[row]);
        }
    }
}

// Layer-1 aggregation + epilogue, wave-per-node, register accumulation
// (R11-proven form: coalesced index load per 64 edges + shfl broadcast,
// 8 independent ushort gathers in flight).
__launch_bounds__(256)
__global__ void k_agg1(const unsigned short* __restrict__ hb,
                       const float* __restrict__ dinv,
                       const int* __restrict__ start,
                       const int* __restrict__ srcSorted,
                       const void* b1, const void* W2, float* __restrict__ sbuf2,
                       const int* flags, int N) {
    int lane = threadIdx.x & 63;
    int node = (blockIdx.x * blockDim.x + threadIdx.x) >> 6;
    if (node >= N) return;
    int isbf = flags[1];
    float di = dinv[node];
    int base = start[node], cnt = start[node + 1] - base;
    float acc = bf2f(hb[(long long)node * 64 + lane]);  // self-loop: *di in epilogue
    for (int c = 0; c < cnt; c += 64) {
        int t = c + lane;
        int sidx = (t < cnt) ? srcSorted[base + t] : 0;
        int m = cnt - c; if (m > 64) m = 64;
        int t2 = 0;
        for (; t2 + 8 <= m; t2 += 8) {
            int s0 = __shfl(sidx, t2 + 0), s1 = __shfl(sidx, t2 + 1);
            int s2 = __shfl(sidx, t2 + 2), s3 = __shfl(sidx, t2 + 3);
            int s4 = __shfl(sidx, t2 + 4), s5 = __shfl(sidx, t2 + 5);
            int s6 = __shfl(sidx, t2 + 6), s7 = __shfl(sidx, t2 + 7);
            unsigned short v0 = hb[(long long)s0 * 64 + lane];
            unsigned short v1 = hb[(long long)s1 * 64 + lane];
            unsigned short v2 = hb[(long long)s2 * 64 + lane];
            unsigned short v3 = hb[(long long)s3 * 64 + lane];
            unsigned short v4 = hb[(long long)s4 * 64 + lane];
            unsigned short v5 = hb[(long long)s5 * 64 + lane];
            unsigned short v6 = hb[(long long)s6 * 64 + lane];
            unsigned short v7 = hb[(long long)s7 * 64 + lane];
            acc += bf2f(v0); acc += bf2f(v1); acc += bf2f(v2); acc += bf2f(v3);
            acc += bf2f(v4); acc += bf2f(v5); acc += bf2f(v6); acc += bf2f(v7);
        }
        for (; t2 < m; ++t2) {
            int s0 = __shfl(sidx, t2);
            acc += bf2f(hb[(long long)s0 * 64 + lane]);
        }
    }
    float v = acc * di + loadF(b1, lane, isbf);
    v = fmaxf(v, 0.f);
    float p = v * loadF(W2, lane, isbf);
    #pragma unroll
    for (int o = 32; o >= 1; o >>= 1) p += __shfl_xor(p, o);
    if (lane == 0) sbuf2[node] = p * di;
}

// Layer-2: out[i] = (sum_src sbuf2[src] + sbuf2[i]) * dinv[i] + b2.
__launch_bounds__(256)
__global__ void k_agg2(const float* __restrict__ sbuf2, const float* __restrict__ dinv,
                       const int* __restrict__ start,
                       const int* __restrict__ srcSorted,
                       const void* b2, void* out, const int* flags, int N) {
    int lane = threadIdx.x & 63;
    int node = (blockIdx.x * blockDim.x + threadIdx.x) >> 6;
    if (node >= N) return;
    int isbf = flags[1];
    float di = dinv[node];
    int base = start[node], cnt = start[node + 1] - base;
    float part = 0.f;
    for (int t = lane; t < cnt; t += 64) part += sbuf2[srcSorted[base + t]];
    #pragma unroll
    for (int o = 32; o >= 1; o >>= 1) part += __shfl_xor(part, o);
    if (lane == 0) {
        float o_ = (part + sbuf2[node]) * di + loadF(b2, 0, isbf);
        if (isbf) ((unsigned short*)out)[node] = f2bf(o_);
        else      ((float*)out)[node] = o_;
    }
}

extern "C" void kernel_launch(void* const* d_in, const int* in_sizes, int n_in,
                              void* d_out, int out_size, void* d_ws, size_t ws_size,
                              hipStream_t stream) {
    const void* x  = d_in[0];
    const void* e  = d_in[1];
    const void* W1 = d_in[2];
    const void* b1 = d_in[3];
    const void* W2 = d_in[4];
    const void* b2 = d_in[5];
    int N = in_sizes[0] / 128;     // 100000
    int E = in_sizes[1] / 2;       // 3200000
    int B  = (N + 511) / 512;      // 196 buckets of 512 nodes
    int HB = (E + 4095) / 4096;    // 782 hist blocks
    int M  = B * HB;               // 153,272
    int nP = (M + 255) / 256;      // 599 (<=8192)
    int NB = B * 512;              // 100,352 padded nodes
    int EP = ((E + 255) / 256) * 256;
    int RB = (N + 15) / 16;        // 6250 row-blocks
    int GG = (RB + 3) / 4;         // 1563 blocks: one row-block per wave

    // Workspace (~29 MB; 40.4 MB proven safe, 52.8 MB crashes):
    int*   wsI         = (int*)d_ws;
    int*   flags       = wsI;                              // 256
    unsigned short* wT = (unsigned short*)(wsI + 256);     // 8192 ushorts (16KB)
    int*   histT       = wsI + 256 + 4096;                 // M rounded
    int*   partial     = histT + ((M + 255) / 256) * 256;  // nP rounded
    int*   bucketStart = partial + ((nP + 255) / 256) * 256;  // B+1 -> 1040
    float* dinv        = (float*)(bucketStart + 1040);     // NB
    float* sbuf2       = dinv + NB;                        // NB
    int*   start       = (int*)(sbuf2 + NB);               // NB + 256
    int*   srcSorted   = start + NB + 256;                 // EP
    int*   part        = srcSorted + EP;                   // EP (12.8 MB)
    unsigned short* hb = (unsigned short*)part;            // N*64 bf16, ALIASES part

    hipLaunchKernelGGL(k_detect, dim3(1), dim3(64), 0, stream, e, x, flags);
    hipLaunchKernelGGL(k_prep, dim3(1), dim3(256), 0, stream, W1, wT, flags);
    hipLaunchKernelGGL(k_hist, dim3(HB), dim3(256), 0, stream, e, histT, flags, E, B, HB);
    hipLaunchKernelGGL(k_scanA, dim3(nP), dim3(256), 0, stream, histT, partial, M);
    hipLaunchKernelGGL(k_scanB, dim3(1), dim3(1024), 0, stream, partial, nP);
    hipLaunchKernelGGL(k_scanC, dim3(nP), dim3(256), 0, stream,
                       histT, partial, bucketStart, M, HB, B, E);
    hipLaunchKernelGGL(k_part, dim3(HB), dim3(256), 0, stream, e, histT, part, flags, E, B, HB);
    hipLaunchKernelGGL(k_sort2, dim3(B), dim3(512), 0, stream,
                       part, bucketStart, srcSorted, start, dinv, N, B);
    hipLaunchKernelGGL(k_gemm_bf, dim3(GG), dim3(256), 0, stream,
                       x, wT, dinv, hb, flags, N);
    hipLaunchKernelGGL(k_gemm_f32, dim3(2048), dim3(256), 0, stream,
                       x, W1, dinv, hb, flags, N);
    hipLaunchKernelGGL(k_agg1, dim3((N + 3) / 4), dim3(256), 0, stream,
                       hb, dinv, start, srcSorted, b1, W2, sbuf2, flags, N);
    hipLaunchKernelGGL(k_agg2, dim3((N + 3) / 4), dim3(256), 0, stream,
                       sbuf2, dinv, start, srcSorted, b2, d_out, flags, N);
}

// Round 14
// 359.186 us; speedup vs baseline: 1.0506x; 1.0089x over previous
//
#include <hip/hip_runtime.h>
#include <hip/hip_bf16.h>

// GCN 2-layer on MI355X — global-atomic-free CSR build + register-acc aggregation.
// R5: global atomicAdd walled ~24 ops/ns device-wide -> no global atomics.
// R6: bucketed LDS-atomic aggregation FAILED (no TLP + in-order LDS pipe).
// R7/R8: hist->scan->part->sort2 CSR + wave-per-node register-acc agg.
// R9/R10: MFMA gemm spill-bound at 98us (frag cache > VGPR budget).
// R11: LDS-free MFMA gemm -> gemm off top-5; agg1 89us @ 3.36 TB/s.
// R12: wide-gather agg1 REGRESSED: VMEM index loads entered the gather
//      dependency chain. Keep shfl-broadcast index path.
// R13: 512-node buckets: -15us on the partition pipeline. agg1 89us remains.
// R14: agg1 gather pipeline depth 8 -> 16 (16 shfls, then 16 independent
//      ushort gathers in flight, then 16 accumulates). Tests per-wave
//      outstanding-entry limit vs L2-miss-path BW wall.

typedef short s8_t __attribute__((ext_vector_type(8)));
typedef float f4_t __attribute__((ext_vector_type(4)));

__device__ __forceinline__ float bf2f(unsigned short u) {
    union { unsigned int u; float f; } c; c.u = ((unsigned int)u) << 16; return c.f;
}
__device__ __forceinline__ unsigned short f2bf(float f) {
    union { float f; unsigned int u; } c; c.f = f;
    unsigned int u = c.u;
    unsigned int r = (u + 0x7fffu + ((u >> 16) & 1u)) >> 16;  // round-nearest-even
    return (unsigned short)r;
}
__device__ __forceinline__ float loadF(const void* p, int i, int isbf) {
    return isbf ? bf2f(((const unsigned short*)p)[i]) : ((const float*)p)[i];
}
__device__ __forceinline__ int edgeIdx(const void* e, long long i, int is64) {
    return is64 ? (int)((const long long*)e)[i] : ((const int*)e)[i];
}

// flags[0] = edge indices are int64; flags[1] = float tensors are bf16
__global__ void k_detect(const void* e, const void* x, int* flags) {
    int lane = threadIdx.x;  // blockDim = 64
    unsigned int ew = ((const unsigned int*)e)[2 * lane + 1];
    unsigned long long nz = __ballot(ew != 0);
    unsigned int xw = ((const unsigned int*)x)[lane];
    unsigned int low = xw & 0xffffu;
    unsigned int e8 = (low >> 7) & 0xffu;
    bool plaus = (low == 0u) || (e8 >= 110u && e8 <= 135u);
    unsigned long long pl = __ballot(plaus);
    if (lane == 0) {
        flags[0] = (nz == 0ull) ? 1 : 0;
        flags[1] = (__popcll(pl) > 32) ? 1 : 0;
    }
}

// W1^T into workspace (bf16 only): wT[n][k] = W1[k][n]. 64x128 ushorts.
__global__ void k_prep(const void* W1, unsigned short* __restrict__ wT,
                       const int* flags) {
    if (!flags[1]) return;
    int tid = threadIdx.x;
    const unsigned short* w = (const unsigned short*)W1;
    for (int idx = tid; idx < 128 * 64; idx += 256) {
        int k = idx >> 6, n = idx & 63;
        wT[n * 128 + k] = w[idx];
    }
}

// Per-block LDS histogram over B coarse buckets (dst>>9); hist[bucket][block].
__launch_bounds__(256)
__global__ void k_hist(const void* e, int* __restrict__ histT, const int* flags,
                       int E, int B, int HB) {
    __shared__ int hist[1024];
    int tid = threadIdx.x;
    int is64 = flags[0];
    for (int f = tid; f < B; f += 256) hist[f] = 0;
    __syncthreads();
    int base = blockIdx.x * 4096;
    #pragma unroll
    for (int k = 0; k < 16; ++k) {
        int i = base + k * 256 + tid;
        if (i < E) {
            int d = edgeIdx(e, (long long)E + i, is64);
            atomicAdd(&hist[d >> 9], 1);   // LDS atomic
        }
    }
    __syncthreads();
    for (int f = tid; f < B; f += 256)
        histT[(long long)f * HB + blockIdx.x] = hist[f];
}

// Exclusive scan over M = B*HB ints, level A.
__global__ void k_scanA(int* __restrict__ data, int* __restrict__ partial, int M) {
    __shared__ int s[256];
    int tid = threadIdx.x;
    int i = blockIdx.x * 256 + tid;
    int v = (i < M) ? data[i] : 0;
    s[tid] = v; __syncthreads();
    for (int off = 1; off < 256; off <<= 1) {
        int t = (tid >= off) ? s[tid - off] : 0;
        __syncthreads(); s[tid] += t; __syncthreads();
    }
    if (i < M) data[i] = s[tid] - v;
    if (tid == 255) partial[blockIdx.x] = s[255];
}

// Level B: in-place exclusive scan of nP partials (nP <= 8192).
__global__ void k_scanB(int* __restrict__ partial, int nP) {
    __shared__ int s[1024];
    int tid = threadIdx.x;
    int C = (nP + 1023) >> 10;
    int base = tid * C;
    int v[8]; int tot = 0;
    for (int j = 0; j < C; ++j) { v[j] = (base + j < nP) ? partial[base + j] : 0; tot += v[j]; }
    s[tid] = tot; __syncthreads();
    for (int off = 1; off < 1024; off <<= 1) {
        int t = (tid >= off) ? s[tid - off] : 0;
        __syncthreads(); s[tid] += t; __syncthreads();
    }
    int run = s[tid] - tot;
    for (int j = 0; j < C; ++j) { if (base + j < nP) { int tmp = v[j]; partial[base + j] = run; run += tmp; } }
}

// Level C: add block bases; extract bucketStart.
__global__ void k_scanC(int* __restrict__ data, const int* __restrict__ partial,
                        int* __restrict__ bucketStart, int M, int HB, int B, int E) {
    int f = blockIdx.x * 256 + threadIdx.x;
    if (f < M) {
        int val = data[f] + partial[f >> 8];
        data[f] = val;
        int q = f / HB;
        if (f - q * HB == 0) bucketStart[q] = val;
    }
    if (f == 0) bucketStart[B] = E;
}

// Partition: pos = scanned[bucket][block] + LDS-atomic rank.
// part[pos] = src | (dstLocal << 17)   (requires N <= 2^17).
__launch_bounds__(256)
__global__ void k_part(const void* e, const int* __restrict__ histT,
                       int* __restrict__ part, const int* flags,
                       int E, int B, int HB) {
    __shared__ int lcur[1024];
    int tid = threadIdx.x;
    int is64 = flags[0];
    for (int f = tid; f < B; f += 256)
        lcur[f] = histT[(long long)f * HB + blockIdx.x];
    __syncthreads();
    int base = blockIdx.x * 4096;
    #pragma unroll
    for (int k = 0; k < 16; ++k) {
        int i = base + k * 256 + tid;
        if (i < E) {
            int s = edgeIdx(e, i, is64);
            int d = edgeIdx(e, (long long)E + i, is64);
            int pos = atomicAdd(&lcur[d >> 9], 1);   // LDS atomic
            part[pos] = s | ((d & 511) << 17);
        }
    }
}

// Block-per-bucket second sort (512 nodes/bucket): LDS 512-counter hist +
// parallel exclusive scan + LDS-rank scatter -> dst-sorted srcSorted[];
// write start[node] and dinv[node].
__launch_bounds__(512)
__global__ void k_sort2(const int* __restrict__ part, const int* __restrict__ bucketStart,
                        int* __restrict__ srcSorted, int* __restrict__ start,
                        float* __restrict__ dinv, int N, int B) {
    __shared__ int cnt[512];
    __shared__ int s[512];
    __shared__ int cur[512];
    int tid = threadIdx.x, b = blockIdx.x;
    cnt[tid] = 0;
    __syncthreads();
    int lo = bucketStart[b], hi = bucketStart[b + 1];
    for (int idx = lo + tid; idx < hi; idx += 512)
        atomicAdd(&cnt[(part[idx] >> 17) & 511], 1);
    __syncthreads();
    int v = cnt[tid];
    s[tid] = v; __syncthreads();
    for (int off = 1; off < 512; off <<= 1) {
        int t = (tid >= off) ? s[tid - off] : 0;
        __syncthreads(); s[tid] += t; __syncthreads();
    }
    int base_ = lo + s[tid] - v;   // exclusive-scan position
    cur[tid] = base_;
    int node = b * 512 + tid;
    if (node < N) {
        start[node] = base_;
        dinv[node] = rsqrtf((float)(v + 1));  // +1 self-loop
    }
    if (b == 0 && tid == 0) start[N] = bucketStart[B];  // = E
    __syncthreads();
    for (int idx = lo + tid; idx < hi; idx += 512) {
        int pw = part[idx];
        int pos = atomicAdd(&cur[(pw >> 17) & 511], 1);  // LDS atomic w/ return
        srcSorted[pos] = pw & 0x1FFFF;
    }
}

// bf16 MFMA GEMM, LDS-FREE: hb[row][n] = bf16((x@W1)[row][n] * dinv[row]).
__launch_bounds__(256)
__global__ void k_gemm_bf(const void* x, const unsigned short* __restrict__ wT,
                          const float* __restrict__ dinv,
                          unsigned short* __restrict__ hb, const int* flags, int N) {
    if (!flags[1]) return;
    int tid = threadIdx.x;
    int lane = tid & 63, wv = tid >> 6;
    int q = lane >> 4, r = lane & 15;
    const unsigned short* xb = (const unsigned short*)x;
    int gw = blockIdx.x * 4 + wv;
    int nW = gridDim.x * 4;
    int RB = (N + 15) >> 4;
    for (int rb = gw; rb < RB; rb += nW) {
        int row0 = rb * 16;
        int arow = row0 + r;
        s8_t a[4];
        #pragma unroll
        for (int kk = 0; kk < 4; ++kk)
            a[kk] = (arow < N)
                ? *(const s8_t*)&xb[(long long)arow * 128 + kk * 32 + q * 8]
                : (s8_t)(short)0;
        f4_t acc[4];
        #pragma unroll
        for (int nt = 0; nt < 4; ++nt) acc[nt] = (f4_t){0.f, 0.f, 0.f, 0.f};
        #pragma unroll
        for (int nt = 0; nt < 4; ++nt) {
            #pragma unroll
            for (int kk = 0; kk < 4; ++kk) {
                s8_t b = *(const s8_t*)&wT[(nt * 16 + r) * 128 + kk * 32 + q * 8];
                acc[nt] = __builtin_amdgcn_mfma_f32_16x16x32_bf16(a[kk], b, acc[nt], 0, 0, 0);
            }
        }
        #pragma unroll
        for (int reg = 0; reg < 4; ++reg) {
            int row = row0 + q * 4 + reg;
            if (row < N) {
                float dv = dinv[row];
                #pragma unroll
                for (int nt = 0; nt < 4; ++nt)
                    hb[(long long)row * 64 + nt * 16 + r] = f2bf(acc[nt][reg] * dv);
            }
        }
    }
}

// f32 fallback GEMM (LDS-VALU loop). Early-exit if bf16.
__launch_bounds__(256)
__global__ void k_gemm_f32(const void* x, const void* W1, const float* __restrict__ dinv,
                           unsigned short* __restrict__ hb, const int* flags, int N) {
    if (flags[1]) return;
    __shared__ float Wl[128 * 64];
    __shared__ float xr[4][128];
    int tid = threadIdx.x;
    for (int idx = tid; idx < 128 * 64; idx += 256) Wl[idx] = ((const float*)W1)[idx];
    int w = tid >> 6, lane = tid & 63;
    for (int rb = blockIdx.x * 4; rb < N; rb += gridDim.x * 4) {
        int row = rb + w;
        bool active = row < N;
        __syncthreads();
        if (active) {
            xr[w][lane]      = ((const float*)x)[(long long)row * 128 + lane];
            xr[w][lane + 64] = ((const float*)x)[(long long)row * 128 + 64 + lane];
        }
        __syncthreads();
        if (active) {
            float acc = 0.f;
            #pragma unroll
            for (int k = 0; k < 128; ++k)
                acc += xr[w][k] * Wl[k * 64 + lane];
            hb[(long long)row * 64 + lane] = f2bf(acc * dinv[row]);
        }
    }
}

// Layer-1 aggregation + epilogue, wave-per-node, register accumulation.
// R14: 16-deep gather pipeline (16 shfls -> 16 independent gathers -> 16 adds).
__launch_bounds__(256)
__global__ void k_agg1(const unsigned short* __restrict__ hb,
                       const float* __restrict__ dinv,
                       const int* __restrict__ start,
                       const int* __restrict__ srcSorted,
                       const void* b1, const void* W2, float* __restrict__ sbuf2,
                       const int* flags, int N) {
    int lane = threadIdx.x & 63;
    int node = (blockIdx.x * blockDim.x + threadIdx.x) >> 6;
    if (node >= N) return;
    int isbf = flags[1];
    float di = dinv[node];
    int base = start[node], cnt = start[node + 1] - base;
    float acc = bf2f(hb[(long long)node * 64 + lane]);  // self-loop: *di in epilogue
    for (int c = 0; c < cnt; c += 64) {
        int t = c + lane;
        int sidx = (t < cnt) ? srcSorted[base + t] : 0;
        int m = cnt - c; if (m > 64) m = 64;
        int t2 = 0;
        for (; t2 + 16 <= m; t2 += 16) {
            int s0  = __shfl(sidx, t2 + 0),  s1  = __shfl(sidx, t2 + 1);
            int s2  = __shfl(sidx, t2 + 2),  s3  = __shfl(sidx, t2 + 3);
            int s4  = __shfl(sidx, t2 + 4),  s5  = __shfl(sidx, t2 + 5);
            int s6  = __shfl(sidx, t2 + 6),  s7  = __shfl(sidx, t2 + 7);
            int s8  = __shfl(sidx, t2 + 8),  s9  = __shfl(sidx, t2 + 9);
            int s10 = __shfl(sidx, t2 + 10), s11 = __shfl(sidx, t2 + 11);
            int s12 = __shfl(sidx, t2 + 12), s13 = __shfl(sidx, t2 + 13);
            int s14 = __shfl(sidx, t2 + 14), s15 = __shfl(sidx, t2 + 15);
            unsigned short v0  = hb[(long long)s0  * 64 + lane];
            unsigned short v1  = hb[(long long)s1  * 64 + lane];
            unsigned short v2  = hb[(long long)s2  * 64 + lane];
            unsigned short v3  = hb[(long long)s3  * 64 + lane];
            unsigned short v4  = hb[(long long)s4  * 64 + lane];
            unsigned short v5  = hb[(long long)s5  * 64 + lane];
            unsigned short v6  = hb[(long long)s6  * 64 + lane];
            unsigned short v7  = hb[(long long)s7  * 64 + lane];
            unsigned short v8  = hb[(long long)s8  * 64 + lane];
            unsigned short v9  = hb[(long long)s9  * 64 + lane];
            unsigned short v10 = hb[(long long)s10 * 64 + lane];
            unsigned short v11 = hb[(long long)s11 * 64 + lane];
            unsigned short v12 = hb[(long long)s12 * 64 + lane];
            unsigned short v13 = hb[(long long)s13 * 64 + lane];
            unsigned short v14 = hb[(long long)s14 * 64 + lane];
            unsigned short v15 = hb[(long long)s15 * 64 + lane];
            acc += bf2f(v0);  acc += bf2f(v1);  acc += bf2f(v2);  acc += bf2f(v3);
            acc += bf2f(v4);  acc += bf2f(v5);  acc += bf2f(v6);  acc += bf2f(v7);
            acc += bf2f(v8);  acc += bf2f(v9);  acc += bf2f(v10); acc += bf2f(v11);
            acc += bf2f(v12); acc += bf2f(v13); acc += bf2f(v14); acc += bf2f(v15);
        }
        for (; t2 + 8 <= m; t2 += 8) {
            int s0 = __shfl(sidx, t2 + 0), s1 = __shfl(sidx, t2 + 1);
            int s2 = __shfl(sidx, t2 + 2), s3 = __shfl(sidx, t2 + 3);
            int s4 = __shfl(sidx, t2 + 4), s5 = __shfl(sidx, t2 + 5);
            int s6 = __shfl(sidx, t2 + 6), s7 = __shfl(sidx, t2 + 7);
            unsigned short v0 = hb[(long long)s0 * 64 + lane];
            unsigned short v1 = hb[(long long)s1 * 64 + lane];
            unsigned short v2 = hb[(long long)s2 * 64 + lane];
            unsigned short v3 = hb[(long long)s3 * 64 + lane];
            unsigned short v4 = hb[(long long)s4 * 64 + lane];
            unsigned short v5 = hb[(long long)s5 * 64 + lane];
            unsigned short v6 = hb[(long long)s6 * 64 + lane];
            unsigned short v7 = hb[(long long)s7 * 64 + lane];
            acc += bf2f(v0); acc += bf2f(v1); acc += bf2f(v2); acc += bf2f(v3);
            acc += bf2f(v4); acc += bf2f(v5); acc += bf2f(v6); acc += bf2f(v7);
        }
        for (; t2 < m; ++t2) {
            int s0 = __shfl(sidx, t2);
            acc += bf2f(hb[(long long)s0 * 64 + lane]);
        }
    }
    float v = acc * di + loadF(b1, lane, isbf);
    v = fmaxf(v, 0.f);
    float p = v * loadF(W2, lane, isbf);
    #pragma unroll
    for (int o = 32; o >= 1; o >>= 1) p += __shfl_xor(p, o);
    if (lane == 0) sbuf2[node] = p * di;
}

// Layer-2: out[i] = (sum_src sbuf2[src] + sbuf2[i]) * dinv[i] + b2.
__launch_bounds__(256)
__global__ void k_agg2(const float* __restrict__ sbuf2, const float* __restrict__ dinv,
                       const int* __restrict__ start,
                       const int* __restrict__ srcSorted,
                       const void* b2, void* out, const int* flags, int N) {
    int lane = threadIdx.x & 63;
    int node = (blockIdx.x * blockDim.x + threadIdx.x) >> 6;
    if (node >= N) return;
    int isbf = flags[1];
    float di = dinv[node];
    int base = start[node], cnt = start[node + 1] - base;
    float part = 0.f;
    for (int t = lane; t < cnt; t += 64) part += sbuf2[srcSorted[base + t]];
    #pragma unroll
    for (int o = 32; o >= 1; o >>= 1) part += __shfl_xor(part, o);
    if (lane == 0) {
        float o_ = (part + sbuf2[node]) * di + loadF(b2, 0, isbf);
        if (isbf) ((unsigned short*)out)[node] = f2bf(o_);
        else      ((float*)out)[node] = o_;
    }
}

extern "C" void kernel_launch(void* const* d_in, const int* in_sizes, int n_in,
                              void* d_out, int out_size, void* d_ws, size_t ws_size,
                              hipStream_t stream) {
    const void* x  = d_in[0];
    const void* e  = d_in[1];
    const void* W1 = d_in[2];
    const void* b1 = d_in[3];
    const void* W2 = d_in[4];
    const void* b2 = d_in[5];
    int N = in_sizes[0] / 128;     // 100000
    int E = in_sizes[1] / 2;       // 3200000
    int B  = (N + 511) / 512;      // 196 buckets of 512 nodes
    int HB = (E + 4095) / 4096;    // 782 hist blocks
    int M  = B * HB;               // 153,272
    int nP = (M + 255) / 256;      // 599 (<=8192)
    int NB = B * 512;              // 100,352 padded nodes
    int EP = ((E + 255) / 256) * 256;
    int RB = (N + 15) / 16;        // 6250 row-blocks
    int GG = (RB + 3) / 4;         // 1563 blocks: one row-block per wave

    // Workspace (~29 MB; 40.4 MB proven safe, 52.8 MB crashes):
    int*   wsI         = (int*)d_ws;
    int*   flags       = wsI;                              // 256
    unsigned short* wT = (unsigned short*)(wsI + 256);     // 8192 ushorts (16KB)
    int*   histT       = wsI + 256 + 4096;                 // M rounded
    int*   partial     = histT + ((M + 255) / 256) * 256;  // nP rounded
    int*   bucketStart = partial + ((nP + 255) / 256) * 256;  // B+1 -> 1040
    float* dinv        = (float*)(bucketStart + 1040);     // NB
    float* sbuf2       = dinv + NB;                        // NB
    int*   start       = (int*)(sbuf2 + NB);               // NB + 256
    int*   srcSorted   = start + NB + 256;                 // EP
    int*   part        = srcSorted + EP;                   // EP (12.8 MB)
    unsigned short* hb = (unsigned short*)part;            // N*64 bf16, ALIASES part

    hipLaunchKernelGGL(k_detect, dim3(1), dim3(64), 0, stream, e, x, flags);
    hipLaunchKernelGGL(k_prep, dim3(1), dim3(256), 0, stream, W1, wT, flags);
    hipLaunchKernelGGL(k_hist, dim3(HB), dim3(256), 0, stream, e, histT, flags, E, B, HB);
    hipLaunchKernelGGL(k_scanA, dim3(nP), dim3(256), 0, stream, histT, partial, M);
    hipLaunchKernelGGL(k_scanB, dim3(1), dim3(1024), 0, stream, partial, nP);
    hipLaunchKernelGGL(k_scanC, dim3(nP), dim3(256), 0, stream,
                       histT, partial, bucketStart, M, HB, B, E);
    hipLaunchKernelGGL(k_part, dim3(HB), dim3(256), 0, stream, e, histT, part, flags, E, B, HB);
    hipLaunchKernelGGL(k_sort2, dim3(B), dim3(512), 0, stream,
                       part, bucketStart, srcSorted, start, dinv, N, B);
    hipLaunchKernelGGL(k_gemm_bf, dim3(GG), dim3(256), 0, stream,
                       x, wT, dinv, hb, flags, N);
    hipLaunchKernelGGL(k_gemm_f32, dim3(2048), dim3(256), 0, stream,
                       x, W1, dinv, hb, flags, N);
    hipLaunchKernelGGL(k_agg1, dim3((N + 3) / 4), dim3(256), 0, stream,
                       hb, dinv, start, srcSorted, b1, W2, sbuf2, flags, N);
    hipLaunchKernelGGL(k_agg2, dim3((N + 3) / 4), dim3(256), 0, stream,
                       sbuf2, dinv, start, srcSorted, b2, d_out, flags, N);
}